// Round 10
// baseline (26.873 us; speedup 1.0000x reference)
//
#include <hip/hip_runtime.h>
#include <math.h>

// PoolingConnection fused: out[k,i,j] = max(s[k, 6i:6i+64, 6j:6j+64]) clipped at 384.
// F=128, H=W=384, stride=6, window=64, out=[128,64,64].
//
// H = 64 segments of exactly 6 rows. out[i] = max(segm[i..i+9], segp[i+10])
// (segments > 63 -> -inf). segm[g] = 2D max of rows 6g..6g+5 (W-pooled),
// segp[g] = rows 6g..6g+3 only. Per segment (one wave): lane l owns cols
// 6l..6l+5 (3x float2), vertical 6-row max in registers, then the proven
// shuffle sliding-window (lanes j..j+9 full + first-4-cols of lane j+10).
//
// ZERO-HALO, ZERO-SYNC tiling: one block per FEATURE (128 blocks x 1024
// threads, 64 segs / 16 waves = 4 each, every input byte read exactly once).
// ROUND-10 CHANGE (single, A/B vs round 9): input loads are NON-TEMPORAL
// (nt flag) -- the stream has zero reuse, so bypass L2 allocation. Tests
// whether the flat ~4.9-5.3 TB/s read ceiling (vs 6.9 TB/s write fills)
// is an L2-path artifact.

constexpr int F  = 128;
constexpr int H  = 384;
constexpr int W  = 384;
constexpr int ST = 6;
constexpr int OH = 64;
constexpr int OW = 64;

constexpr int NSEG   = 64;        // segments per feature (all of H)
constexpr int SEGPAD = NSEG + 10; // -inf padded for fixed 10-tap combine

#define NINF (-__builtin_huge_valf())

typedef float f2_t __attribute__((ext_vector_type(2)));

// shuffle value from lane (lane+d); lanes beyond 63 contribute -inf
// (implements the right-edge window clipping for free).
__device__ __forceinline__ float sh_ninf(float v, int lane, int d) {
    float r = __shfl(v, lane + d, 64);
    return (lane + d > 63) ? NINF : r;
}

// sliding max over lanes [l..l+9] of m, plus first-4-cols of lane l+10
__device__ __forceinline__ float slide_window(float m, float p3, int lane) {
    const float a1 = fmaxf(m,  sh_ninf(m,  lane, 1));   // [l, l+1]
    const float a2 = fmaxf(a1, sh_ninf(a1, lane, 2));   // [l .. l+3]
    const float a3 = fmaxf(a2, sh_ninf(a2, lane, 4));   // [l .. l+7]
    const float a4 = fmaxf(a3, sh_ninf(a1, lane, 8));   // [l .. l+9]
    return fmaxf(a4, sh_ninf(p3, lane, 10));            // + 4 cols of l+10
}

__global__ __launch_bounds__(1024) void pool_fused_kernel(const float* __restrict__ s,
                                                          float* __restrict__ out) {
    __shared__ float segm[SEGPAD][64];   // 18.5 KiB
    __shared__ float segp[SEGPAD][64];   // 18.5 KiB

    const int k    = blockIdx.x;
    const int tid  = threadIdx.x;
    const int wv   = tid >> 6;        // 0..15
    const int lane = tid & 63;

    // -inf pad for segs 64..73 (bottom clipping for out i >= 54)
    for (int job = tid; job < 10 * 64; job += 1024) {
        const int g = NSEG + (job >> 6);
        const int j = job & 63;
        segm[g][j] = NINF;
        segp[g][j] = NINF;
    }

    // ---- Phase 1: exactly 4 segments per wave (gl = wv + 16*it) ----
    const float* base = s + (size_t)k * H * W + lane * 6;
    #pragma unroll
    for (int it = 0; it < 4; ++it) {
        const int gl = wv + it * 16;
        const float* seg = base + (size_t)gl * ST * W;
        float vm6 = NINF, vp6 = NINF;    // rows 0..5: all-6-cols / first-4-cols
        float vm4 = NINF, vp4 = NINF;    // rows 0..3 only
        #pragma unroll
        for (int t = 0; t < 6; ++t) {
            const float* row = seg + (size_t)t * W;
            const f2_t e0 = __builtin_nontemporal_load(
                                reinterpret_cast<const f2_t*>(row));
            const f2_t e1 = __builtin_nontemporal_load(
                                reinterpret_cast<const f2_t*>(row + 2));
            const f2_t e2 = __builtin_nontemporal_load(
                                reinterpret_cast<const f2_t*>(row + 4));
            const float p3 = fmaxf(fmaxf(e0.x, e0.y), fmaxf(e1.x, e1.y));
            const float m  = fmaxf(p3, fmaxf(e2.x, e2.y));
            vm6 = fmaxf(vm6, m);
            vp6 = fmaxf(vp6, p3);
            if (t < 4) { vm4 = fmaxf(vm4, m); vp4 = fmaxf(vp4, p3); }
        }
        segm[gl][lane] = slide_window(vm6, vp6, lane);
        segp[gl][lane] = slide_window(vm4, vp4, lane);
    }
    __syncthreads();

    // ---- Phase 2: out[li] = max(segm[li..li+9], segp[li+10]) ----
    for (int job = tid; job < 64 * 64; job += 1024) {
        const int li = job >> 6;
        const int j  = job & 63;
        float acc = segp[li + 10][j];
        #pragma unroll
        for (int t = 0; t < 10; ++t) acc = fmaxf(acc, segm[li + t][j]);
        out[((size_t)k * OH + li) * OW + j] = acc;   // coalesced
    }
}

extern "C" void kernel_launch(void* const* d_in, const int* in_sizes, int n_in,
                              void* d_out, int out_size, void* d_ws, size_t ws_size,
                              hipStream_t stream) {
    const float* s = (const float*)d_in[0];
    float* out     = (float*)d_out;
    pool_fused_kernel<<<F, 1024, 0, stream>>>(s, out);
}